// Round 1
// baseline (259.396 us; speedup 1.0000x reference)
//
#include <hip/hip_runtime.h>

#define HW 65536
#define CH 64
#define NPIXF 4194304.0f

typedef __attribute__((ext_vector_type(8))) short short8;
typedef __attribute__((ext_vector_type(4))) short short4v;
typedef __attribute__((ext_vector_type(8))) __bf16 bf16x8;
typedef __attribute__((ext_vector_type(4))) float f32x4;

__device__ __forceinline__ unsigned short f2bf(float f) {
  unsigned int u = __builtin_bit_cast(unsigned int, f);
  u += 0x7FFFu + ((u >> 16) & 1u);
  return (unsigned short)(u >> 16);
}
__device__ __forceinline__ float bf2f(unsigned short h) {
  return __builtin_bit_cast(float, ((unsigned int)h) << 16);
}
__device__ __forceinline__ int swz(int p, int cc) { return cc ^ ((p ^ (p >> 3)) & 7); }

// ws layout (floats): [0..15]=sum_x  [16..31]=sumsq_x  [32..47]=sum_h  [48..63]=sumsq_h
//                     [64..127]=u1   [128..191]=v1     [192..207]=u2   [208..223]=v2
// bytes: A1bf (64x64 bf16) @1024, A2bf (16x64 bf16) @9216, t buffer @16384

__global__ void k_pre(const float* __restrict__ w1, const float* __restrict__ b1,
                      const float* __restrict__ s1, const float* __restrict__ gb1,
                      const float* __restrict__ w2, const float* __restrict__ b2,
                      const float* __restrict__ s2, const float* __restrict__ gb2,
                      float* __restrict__ wsf,
                      unsigned short* __restrict__ a1, unsigned short* __restrict__ a2) {
  int t = threadIdx.x;
  if (t < 64) {
    float u = 0.f, v = 0.f;
    for (int c = 0; c < 64; ++c) {
      float w = w1[t * 64 + c];
      float wsc = w * s1[c];
      a1[t * 64 + c] = f2bf(wsc);
      u += wsc;
      v += w * gb1[c];
    }
    wsf[64 + t] = u;
    wsf[128 + t] = b1[t] + v;
  } else if (t < 80) {
    int o = t - 64;
    float u = 0.f, v = 0.f;
    for (int c = 0; c < 64; ++c) {
      float w = (o < 6) ? w2[o * 64 + c] : 0.f;
      float wsc = w * s2[c];
      a2[o * 64 + c] = f2bf(wsc);
      u += wsc;
      v += w * gb2[c];
    }
    wsf[192 + o] = u;
    wsf[208 + o] = ((o < 6) ? b2[o] : 0.f) + v;
  } else if (t < 144) {
    wsf[t - 80] = 0.f;  // zero the 64 accumulator slots
  }
}

// Pass 1: stats of x  +  t = A1 * x  (bf16, stored pixel-major [p][c])
__global__ __launch_bounds__(256) void k1(const float* __restrict__ x,
                                          const unsigned short* __restrict__ a1,
                                          float* __restrict__ wsf,
                                          unsigned short* __restrict__ t, int b0) {
  __shared__ __align__(16) unsigned char tile[128 * 128];  // [128 p][64 c] bf16, swizzled
  __shared__ float red[8];
  const int tid = threadIdx.x;
  const int l = tid & 63, w = tid >> 6;
  const int bloc = blockIdx.y, b = b0 + bloc;
  const int ptile = blockIdx.x * 128;
  const float* xb = x + (size_t)b * CH * HW;

  // A fragments (weights), reused for the whole tile
  bf16x8 af[4][2];
#pragma unroll
  for (int mf = 0; mf < 4; ++mf)
#pragma unroll
    for (int ks = 0; ks < 2; ++ks) {
      int m = mf * 16 + (l & 15);
      af[mf][ks] = *(const bf16x8*)((const unsigned char*)a1 + m * 128 + ks * 64 + (l >> 4) * 16);
    }

  // load x tile: thread owns 8 channels x 4 pixels (8 coalesced float4 row loads)
  const int c0 = (tid >> 5) * 8;
  const int p4 = (tid & 31) * 4;
  f32x4 v[8];
  const float* base = xb + (size_t)c0 * HW + ptile + p4;
#pragma unroll
  for (int i = 0; i < 8; ++i) v[i] = *(const f32x4*)(base + (size_t)i * HW);

  // per-sample stats of x
  float s = 0.f, q = 0.f;
#pragma unroll
  for (int i = 0; i < 8; ++i)
#pragma unroll
    for (int dp = 0; dp < 4; ++dp) { float f = v[i][dp]; s += f; q += f * f; }
#pragma unroll
  for (int off = 32; off > 0; off >>= 1) {
    s += __shfl_down(s, off, 64);
    q += __shfl_down(q, off, 64);
  }
  if (l == 0) { red[w] = s; red[4 + w] = q; }

  // in-register 8x4 transpose -> LDS [p][c] (bf16, XOR-swizzled 16B columns)
#pragma unroll
  for (int dp = 0; dp < 4; ++dp) {
    int p = p4 + dp;
    short8 w8;
#pragma unroll
    for (int i = 0; i < 8; ++i) w8[i] = (short)f2bf(v[i][dp]);
    *(short8*)(tile + p * 128 + swz(p, c0 >> 3) * 16) = w8;
  }
  __syncthreads();

  unsigned short* tb = t + (size_t)bloc * CH * HW;
#pragma unroll
  for (int nf = 0; nf < 2; ++nf) {
    const int pl = w * 32 + nf * 16 + (l & 15);
    bf16x8 bfr[2];
#pragma unroll
    for (int ks = 0; ks < 2; ++ks) {
      int cc = ks * 4 + (l >> 4);
      bfr[ks] = *(const bf16x8*)(tile + pl * 128 + swz(pl, cc) * 16);
    }
#pragma unroll
    for (int mf = 0; mf < 4; ++mf) {
      f32x4 acc = {0.f, 0.f, 0.f, 0.f};
      acc = __builtin_amdgcn_mfma_f32_16x16x32_bf16(af[mf][0], bfr[0], acc, 0, 0, 0);
      acc = __builtin_amdgcn_mfma_f32_16x16x32_bf16(af[mf][1], bfr[1], acc, 0, 0, 0);
      short4v sv;
#pragma unroll
      for (int r = 0; r < 4; ++r) sv[r] = (short)f2bf(acc[r]);
      int o0 = mf * 16 + (l >> 4) * 4;
      *(short4v*)(tb + (size_t)(ptile + pl) * CH + o0) = sv;  // t[p][c], pixel-major
    }
  }

  if (tid == 0) {
    atomicAdd(wsf + b, red[0] + red[1] + red[2] + red[3]);
    atomicAdd(wsf + 16 + b, red[4] + red[5] + red[6] + red[7]);
  }
}

// Pass 2: h = silu(rs1*t + c1), accumulate per-sample sum/sumsq of h
__global__ __launch_bounds__(256) void k2(const unsigned short* __restrict__ t,
                                          float* __restrict__ wsf, int b0) {
  __shared__ float c1s[64];
  __shared__ float red[8];
  const int tid = threadIdx.x;
  const int l = tid & 63, w = tid >> 6;
  const int bloc = blockIdx.y, b = b0 + bloc;
  const float m1 = wsf[b] / NPIXF;
  const float rs1 = rsqrtf(wsf[16 + b] / NPIXF - m1 * m1 + 1e-6f);
  if (tid < 64) c1s[tid] = wsf[128 + tid] - rs1 * m1 * wsf[64 + tid];
  __syncthreads();
  const unsigned short* tb = t + (size_t)bloc * CH * HW;
  size_t ch0 = (size_t)blockIdx.x * 2048 + tid;
  float s = 0.f, q = 0.f;
  for (int it = 0; it < 8; ++it) {
    size_t ch = ch0 + (size_t)it * 256;
    short8 tv = *(const short8*)(tb + ch * 8);
    int c0 = (int)(ch & 7) * 8;
#pragma unroll
    for (int i = 0; i < 8; ++i) {
      float z = rs1 * bf2f((unsigned short)tv[i]) + c1s[c0 + i];
      float hh = z / (1.f + __expf(-z));
      s += hh; q += hh * hh;
    }
  }
#pragma unroll
  for (int off = 32; off > 0; off >>= 1) {
    s += __shfl_down(s, off, 64);
    q += __shfl_down(q, off, 64);
  }
  if (l == 0) { red[w] = s; red[4 + w] = q; }
  __syncthreads();
  if (tid == 0) {
    atomicAdd(wsf + 32 + b, red[0] + red[1] + red[2] + red[3]);
    atomicAdd(wsf + 48 + b, red[4] + red[5] + red[6] + red[7]);
  }
}

// Pass 3: out = rs2 * (A2 * silu(rs1*t + c1)) + c2   (t loads are already B-fragments)
__global__ __launch_bounds__(256) void k3(const unsigned short* __restrict__ t,
                                          const unsigned short* __restrict__ a2,
                                          const float* __restrict__ wsf,
                                          float* __restrict__ out, int b0) {
  __shared__ float c1s[64];
  __shared__ float c2s[8];
  const int tid = threadIdx.x;
  const int l = tid & 63, w = tid >> 6;
  const int bloc = blockIdx.y, b = b0 + bloc;
  const int ptile = blockIdx.x * 128;
  const float m1 = wsf[b] / NPIXF;
  const float rs1 = rsqrtf(wsf[16 + b] / NPIXF - m1 * m1 + 1e-6f);
  const float m2 = wsf[32 + b] / NPIXF;
  const float rs2 = rsqrtf(wsf[48 + b] / NPIXF - m2 * m2 + 1e-6f);
  if (tid < 64) c1s[tid] = wsf[128 + tid] - rs1 * m1 * wsf[64 + tid];
  if (tid >= 64 && tid < 72) {
    int o = tid - 64;
    c2s[o] = (o < 6) ? (wsf[208 + o] - rs2 * m2 * wsf[192 + o]) : 0.f;
  }
  __syncthreads();
  bf16x8 a2f[2];
#pragma unroll
  for (int ks = 0; ks < 2; ++ks)
    a2f[ks] = *(const bf16x8*)((const unsigned char*)a2 + (l & 15) * 128 + ks * 64 + (l >> 4) * 16);
  const unsigned short* tb = t + (size_t)bloc * CH * HW;
  float* ob = out + (size_t)b * 6 * HW;
#pragma unroll
  for (int nf = 0; nf < 2; ++nf) {
    const int p = ptile + w * 32 + nf * 16 + (l & 15);
    f32x4 acc = {0.f, 0.f, 0.f, 0.f};
#pragma unroll
    for (int ks = 0; ks < 2; ++ks) {
      const int c0 = ks * 32 + (l >> 4) * 8;
      short8 tv = *(const short8*)(tb + (size_t)p * CH + c0);
      short8 hs;
#pragma unroll
      for (int i = 0; i < 8; ++i) {
        float z = rs1 * bf2f((unsigned short)tv[i]) + c1s[c0 + i];
        float hh = z / (1.f + __expf(-z));
        hs[i] = (short)f2bf(hh);
      }
      acc = __builtin_amdgcn_mfma_f32_16x16x32_bf16(a2f[ks], __builtin_bit_cast(bf16x8, hs), acc, 0, 0, 0);
    }
    const int ob0 = (l >> 4) * 4;
#pragma unroll
    for (int r = 0; r < 4; ++r) {
      int o = ob0 + r;
      if (o < 6) ob[(size_t)o * HW + p] = rs2 * acc[r] + c2s[o];
    }
  }
}

extern "C" void kernel_launch(void* const* d_in, const int* in_sizes, int n_in,
                              void* d_out, int out_size, void* d_ws, size_t ws_size,
                              hipStream_t stream) {
  const float* x  = (const float*)d_in[0];
  const float* s1 = (const float*)d_in[1];
  const float* g1 = (const float*)d_in[2];
  const float* w1 = (const float*)d_in[3];
  const float* b1 = (const float*)d_in[4];
  const float* s2 = (const float*)d_in[5];
  const float* g2 = (const float*)d_in[6];
  const float* w2 = (const float*)d_in[7];
  const float* b2 = (const float*)d_in[8];
  float* out = (float*)d_out;
  float* wsf = (float*)d_ws;
  unsigned short* a1 = (unsigned short*)((char*)d_ws + 1024);
  unsigned short* a2 = (unsigned short*)((char*)d_ws + 9216);
  unsigned short* t  = (unsigned short*)((char*)d_ws + 16384);
  const size_t per_sample = (size_t)CH * HW * sizeof(unsigned short);  // 8 MiB
  int G = 0;
  if (ws_size > 16384) {
    size_t cap = (ws_size - 16384) / per_sample;
    G = (int)(cap > 16 ? 16 : cap);
  }
  if (G < 1) return;  // scratch too small for even one sample's t

  k_pre<<<1, 256, 0, stream>>>(w1, b1, s1, g1, w2, b2, s2, g2, wsf, a1, a2);
  for (int b0 = 0; b0 < 16; b0 += G) {
    int Gi = (16 - b0 < G) ? (16 - b0) : G;
    k1<<<dim3(512, Gi), 256, 0, stream>>>(x, a1, wsf, t, b0);
    k2<<<dim3(256, Gi), 256, 0, stream>>>(t, wsf, b0);
    k3<<<dim3(512, Gi), 256, 0, stream>>>(t, a2, wsf, out, b0);
  }
}